// Round 1
// baseline (1062.548 us; speedup 1.0000x reference)
//
#include <hip/hip_runtime.h>
#include <hip/hip_bf16.h>
#include <stdint.h>

#define NN 50000
#define NE 800000
#define DD 256
#define NL 4
#define NRL 4
#define KT 1280  // NRL*DD + DD

typedef float f32x4 __attribute__((ext_vector_type(4)));
typedef __bf16 bf16x8 __attribute__((ext_vector_type(8)));

static __device__ __forceinline__ unsigned short f2bf(float f) {
  __bf16 h = (__bf16)f;
  return __builtin_bit_cast(unsigned short, h);
}

static __device__ __forceinline__ ushort4 pk4(f32x4 v) {
  ushort4 o;
  o.x = f2bf(v.x); o.y = f2bf(v.y); o.z = f2bf(v.z); o.w = f2bf(v.w);
  return o;
}

static __device__ __forceinline__ void async16(const void* g, void* l) {
  __builtin_amdgcn_global_load_lds(
      (const __attribute__((address_space(1))) unsigned int*)g,
      (__attribute__((address_space(3))) unsigned int*)l, 16, 0, 0);
}

// ---------------- edge preprocessing (once per call) ----------------

__global__ __launch_bounds__(256) void k_hist(const int* __restrict__ ei,
                                              const int* __restrict__ et,
                                              int* __restrict__ cntNR) {
  int e = blockIdx.x * 256 + threadIdx.x;
  if (e >= NE) return;
  int dst = ei[NE + e];
  int r = et[e];
  atomicAdd(&cntNR[dst * 4 + r], 1);
}

__global__ __launch_bounds__(256) void k_scan1(const int* __restrict__ cntNR,
                                               int* __restrict__ offs,
                                               int* __restrict__ bsum) {
  __shared__ int sd[256];
  const int t = threadIdx.x;
  const int n = blockIdx.x * 256 + t;
  int deg = 0;
  if (n < NN) {
    const int* c = cntNR + n * 4;
    deg = c[0] + c[1] + c[2] + c[3];
  }
  sd[t] = deg;
  __syncthreads();
  int val = deg;
  for (int d = 1; d < 256; d <<= 1) {
    int other = (t >= d) ? sd[t - d] : 0;
    __syncthreads();
    val += other;
    sd[t] = val;
    __syncthreads();
  }
  if (n < NN) offs[n] = val - deg;  // exclusive
  if (t == 255) bsum[blockIdx.x] = val;
}

__global__ __launch_bounds__(256) void k_scan2(const int* __restrict__ bsum,
                                               int* __restrict__ boff, int nb) {
  __shared__ int sd[256];
  const int t = threadIdx.x;
  int v = (t < nb) ? bsum[t] : 0;
  sd[t] = v;
  __syncthreads();
  int val = v;
  for (int d = 1; d < 256; d <<= 1) {
    int other = (t >= d) ? sd[t - d] : 0;
    __syncthreads();
    val += other;
    sd[t] = val;
    __syncthreads();
  }
  boff[t] = val - v;  // exclusive
}

__global__ __launch_bounds__(256) void k_scan3(int* __restrict__ offs,
                                               const int* __restrict__ boff,
                                               int* __restrict__ cursor) {
  int n = blockIdx.x * 256 + threadIdx.x;
  if (n < NN) {
    int o = offs[n] + boff[blockIdx.x];
    offs[n] = o;
    cursor[n] = o;
  }
  if (n == 0) offs[NN] = NE;
}

__global__ __launch_bounds__(256) void k_scatter(const int* __restrict__ ei,
                                                 const int* __restrict__ et,
                                                 int* __restrict__ cursor,
                                                 uint32_t* __restrict__ packed) {
  int e = blockIdx.x * 256 + threadIdx.x;
  if (e >= NE) return;
  int src = ei[e];
  int dst = ei[NE + e];
  int r = et[e];
  int pos = atomicAdd(&cursor[dst], 1);
  packed[pos] = (uint32_t)src | ((uint32_t)r << 16);  // src < 65536 ok
}

// Build WbigT[l][o][k] bf16: k<1024 -> weights[l][k>>8][k&255][o], else roots[l][k-1024][o]
__global__ __launch_bounds__(256) void k_wconv(const float* __restrict__ weights,
                                               const float* __restrict__ roots,
                                               __hip_bfloat16* __restrict__ WbigT) {
  int idx = blockIdx.x * 256 + threadIdx.x;
  if (idx >= NL * DD * KT) return;
  int l = idx / (DD * KT);
  int rem = idx - l * (DD * KT);
  int o = rem / KT;
  int k = rem - o * KT;
  float v;
  if (k < NRL * DD) {
    int r = k >> 8, i = k & 255;
    v = weights[(((size_t)(l * NRL + r) * DD) + i) * DD + o];
  } else {
    int i = k - NRL * DD;
    v = roots[((size_t)l * DD + i) * DD + o];
  }
  WbigT[idx] = __float2bfloat16(v);
}

// ---------------- per-layer aggregation: one wave per node ----------------

__global__ __launch_bounds__(256) void k_agg(const float* __restrict__ X,
                                             const uint32_t* __restrict__ packed,
                                             const int* __restrict__ offs,
                                             const int* __restrict__ cntNR,
                                             __hip_bfloat16* __restrict__ Abig) {
  const int wid = (blockIdx.x * 256 + threadIdx.x) >> 6;
  const int lane = threadIdx.x & 63;
  if (wid >= NN) return;
  const int beg = offs[wid];
  const int end = offs[wid + 1];
  const f32x4* __restrict__ Xv = (const f32x4*)X;

  f32x4 a0 = {0.f, 0.f, 0.f, 0.f}, a1 = a0, a2 = a0, a3 = a0;

  uint32_t p = (beg < end) ? packed[beg] : 0u;
  for (int e = beg; e < end; ++e) {
    uint32_t pn = (e + 1 < end) ? packed[e + 1] : 0u;
    const int src = (int)(p & 0xFFFFu);
    const int r = (int)(p >> 16);
    f32x4 v = Xv[src * 64 + lane];
    if (r == 0) a0 += v;
    else if (r == 1) a1 += v;
    else if (r == 2) a2 += v;
    else a3 += v;
    p = pn;
  }

  const int* c = cntNR + wid * 4;
  int c0 = c[0], c1 = c[1], c2 = c[2], c3 = c[3];
  float s0 = 1.0f / (float)(c0 > 1 ? c0 : 1);
  float s1 = 1.0f / (float)(c1 > 1 ? c1 : 1);
  float s2 = 1.0f / (float)(c2 > 1 ? c2 : 1);
  float s3 = 1.0f / (float)(c3 > 1 ? c3 : 1);

  ushort4* Arow = (ushort4*)(Abig + (size_t)wid * KT);
  Arow[0 * 64 + lane] = pk4(a0 * s0);
  Arow[1 * 64 + lane] = pk4(a1 * s1);
  Arow[2 * 64 + lane] = pk4(a2 * s2);
  Arow[3 * 64 + lane] = pk4(a3 * s3);
  // X copy for the root term (cols 1024..1279)
  f32x4 xv = Xv[wid * 64 + lane];
  Arow[256 + lane] = pk4(xv);
}

// ---------------- GEMM + bias + LayerNorm + ELU + residual ----------------
// C[m, n] = A[m, 0:1280] @ WbigT[n, 0:1280]^T ; BM=64, BN=256(all), BK=32

__global__ __launch_bounds__(256) void k_gemm(const __hip_bfloat16* __restrict__ A,
                                              const __hip_bfloat16* __restrict__ Bt,
                                              const float* __restrict__ bias,
                                              const float* __restrict__ gamma,
                                              const float* __restrict__ beta,
                                              const float* __restrict__ Xin,
                                              float* __restrict__ Xout) {
  __shared__ __align__(16) char sA[64 * 64];    // 64 rows x 32 bf16 (64B), chunk-swizzled
  __shared__ __align__(16) char sB[256 * 64];   // 256 rows x 32 bf16
  __shared__ float sRed[64][4];

  const int tid = threadIdx.x;
  const int w = tid >> 6;
  const int lane = tid & 63;
  const int wm = w >> 1, wn = w & 1;
  const int quad = lane >> 4, l15 = lane & 15;
  const int mBase = blockIdx.x * 64;

  // staging lane map: lane i -> row i/4, LDS slot i%4; global chunk = slot ^ ((row>>1)&3)
  const int srow = lane >> 2;
  const int kc = (lane & 3) ^ ((lane >> 3) & 3);

  int am = mBase + w * 16 + srow;
  if (am >= NN) am = NN - 1;  // clamp (stores are guarded)
  const char* agp = (const char*)A + (size_t)am * (KT * 2) + kc * 16;
  const char* bgp0 = (const char*)Bt + (size_t)(w * 64 + 0 + srow) * (KT * 2) + kc * 16;
  const char* bgp1 = (const char*)Bt + (size_t)(w * 64 + 16 + srow) * (KT * 2) + kc * 16;
  const char* bgp2 = (const char*)Bt + (size_t)(w * 64 + 32 + srow) * (KT * 2) + kc * 16;
  const char* bgp3 = (const char*)Bt + (size_t)(w * 64 + 48 + srow) * (KT * 2) + kc * 16;
  char* alp = sA + w * 1024;
  char* blp0 = sB + w * 4096 + 0;
  char* blp1 = sB + w * 4096 + 1024;
  char* blp2 = sB + w * 4096 + 2048;
  char* blp3 = sB + w * 4096 + 3072;

  f32x4 acc[2][8];
#pragma unroll
  for (int i = 0; i < 2; ++i)
#pragma unroll
    for (int j = 0; j < 8; ++j) acc[i][j] = (f32x4){0.f, 0.f, 0.f, 0.f};

  const int aslot = (quad ^ ((l15 >> 1) & 3)) * 16;
  const char* aAddr0 = sA + (wm * 32 + 0 + l15) * 64 + aslot;
  const char* aAddr1 = sA + (wm * 32 + 16 + l15) * 64 + aslot;
  const char* bAddr = sB + (wn * 128 + l15) * 64 + aslot;

  for (int k0 = 0; k0 < KT * 2; k0 += 64) {  // byte offset within a row
    __syncthreads();
    async16(agp + k0, alp);
    async16(bgp0 + k0, blp0);
    async16(bgp1 + k0, blp1);
    async16(bgp2 + k0, blp2);
    async16(bgp3 + k0, blp3);
    __syncthreads();
    bf16x8 a0 = *(const bf16x8*)aAddr0;
    bf16x8 a1 = *(const bf16x8*)aAddr1;
#pragma unroll
    for (int nt = 0; nt < 8; ++nt) {
      bf16x8 b = *(const bf16x8*)(bAddr + nt * 1024);
      acc[0][nt] = __builtin_amdgcn_mfma_f32_16x16x32_bf16(a0, b, acc[0][nt], 0, 0, 0);
      acc[1][nt] = __builtin_amdgcn_mfma_f32_16x16x32_bf16(a1, b, acc[1][nt], 0, 0, 0);
    }
  }

  // ---- epilogue: bias, LN (full 256-wide rows in-block), ELU, residual ----
  float bv[8], gv[8], bev[8];
#pragma unroll
  for (int nt = 0; nt < 8; ++nt) {
    int n = wn * 128 + nt * 16 + l15;
    bv[nt] = bias[n];
    gv[nt] = gamma[n];
    bev[nt] = beta[n];
  }

#pragma unroll
  for (int mt = 0; mt < 2; ++mt) {
#pragma unroll
    for (int reg = 0; reg < 4; ++reg) {
      float s = 0.f, q = 0.f;
#pragma unroll
      for (int nt = 0; nt < 8; ++nt) {
        float v = acc[mt][nt][reg] + bv[nt];
        acc[mt][nt][reg] = v;
        s += v;
        q += v * v;
      }
#pragma unroll
      for (int d = 1; d < 16; d <<= 1) {
        s += __shfl_xor(s, d, 64);
        q += __shfl_xor(q, d, 64);
      }
      if (l15 == 0) {
        int row = wm * 32 + mt * 16 + quad * 4 + reg;
        sRed[row][wn * 2] = s;
        sRed[row][wn * 2 + 1] = q;
      }
    }
  }
  __syncthreads();

#pragma unroll
  for (int mt = 0; mt < 2; ++mt) {
#pragma unroll
    for (int reg = 0; reg < 4; ++reg) {
      int row = wm * 32 + mt * 16 + quad * 4 + reg;
      float ts = sRed[row][0] + sRed[row][2];
      float tq = sRed[row][1] + sRed[row][3];
      float mean = ts * (1.0f / 256.0f);
      float var = tq * (1.0f / 256.0f) - mean * mean;
      float rstd = rsqrtf(var + 1e-5f);
      int m = mBase + row;
      if (m < NN) {
#pragma unroll
        for (int nt = 0; nt < 8; ++nt) {
          int n = wn * 128 + nt * 16 + l15;
          float v = (acc[mt][nt][reg] - mean) * rstd * gv[nt] + bev[nt];
          v = v > 0.0f ? v : (__expf(v) - 1.0f);
          Xout[(size_t)m * 256 + n] = v + Xin[(size_t)m * 256 + n];
        }
      }
    }
  }
}

// ---------------- host side ----------------

extern "C" void kernel_launch(void* const* d_in, const int* in_sizes, int n_in,
                              void* d_out, int out_size, void* d_ws, size_t ws_size,
                              hipStream_t stream) {
  const float* X0 = (const float*)d_in[0];
  const float* weights = (const float*)d_in[1];
  const float* roots = (const float*)d_in[2];
  const float* biases = (const float*)d_in[3];
  const float* ln_g = (const float*)d_in[4];
  const float* ln_b = (const float*)d_in[5];
  const int* eidx = (const int*)d_in[6];
  const int* etyp = (const int*)d_in[7];
  float* out = (float*)d_out;

  char* ws = (char*)d_ws;
  size_t off = 0;
  auto alloc = [&](size_t bytes) -> char* {
    char* p = ws + off;
    off = (off + bytes + 255) & ~(size_t)255;
    return p;
  };
  __hip_bfloat16* Abig = (__hip_bfloat16*)alloc((size_t)NN * KT * 2);          // 128 MB
  __hip_bfloat16* WbigT = (__hip_bfloat16*)alloc((size_t)NL * DD * KT * 2);    // 2.6 MB
  float* Xb0 = (float*)alloc((size_t)NN * DD * 4);                              // 51.2 MB
  float* Xb1 = (float*)alloc((size_t)NN * DD * 4);                              // 51.2 MB
  int* cntNR = (int*)alloc((size_t)NN * 4 * 4);
  int* offs = (int*)alloc((size_t)(NN + 1) * 4);
  int* cursor = (int*)alloc((size_t)NN * 4);
  uint32_t* packed = (uint32_t*)alloc((size_t)NE * 4);
  int* bsum = (int*)alloc(256 * 4);
  int* boff = (int*)alloc(256 * 4);
  (void)ws_size; (void)in_sizes; (void)n_in; (void)out_size;

  hipMemsetAsync(cntNR, 0, (size_t)NN * 16, stream);
  k_hist<<<(NE + 255) / 256, 256, 0, stream>>>(eidx, etyp, cntNR);
  const int NB = (NN + 255) / 256;  // 196
  k_scan1<<<NB, 256, 0, stream>>>(cntNR, offs, bsum);
  k_scan2<<<1, 256, 0, stream>>>(bsum, boff, NB);
  k_scan3<<<NB, 256, 0, stream>>>(offs, boff, cursor);
  k_scatter<<<(NE + 255) / 256, 256, 0, stream>>>(eidx, etyp, cursor, packed);
  k_wconv<<<(NL * DD * KT + 255) / 256, 256, 0, stream>>>(weights, roots, WbigT);

  const float* Xin = X0;
  for (int l = 0; l < NL; ++l) {
    float* Xout = (l == NL - 1) ? out : ((l & 1) ? Xb1 : Xb0);
    k_agg<<<(NN * 64 + 255) / 256, 256, 0, stream>>>(Xin, packed, offs, cntNR, Abig);
    k_gemm<<<(NN + 63) / 64, 256, 0, stream>>>(Abig, WbigT + (size_t)l * DD * KT,
                                               biases + (size_t)l * DD,
                                               ln_g + (size_t)l * DD,
                                               ln_b + (size_t)l * DD, Xin, Xout);
    Xin = Xout;
  }
}

// Round 2
// 1012.439 us; speedup vs baseline: 1.0495x; 1.0495x over previous
//
#include <hip/hip_runtime.h>
#include <hip/hip_bf16.h>
#include <stdint.h>

#define NN 50000
#define NE 800000
#define DD 256
#define NL 4
#define NRL 4
#define KT 1280  // NRL*DD + DD (logical K of the fused GEMM)
#define KA 1024  // NRL*DD (columns stored in Abig; root block comes from Xbf)

typedef float f32x4 __attribute__((ext_vector_type(4)));
typedef __bf16 bf16x8 __attribute__((ext_vector_type(8)));
typedef __bf16 bf16x4 __attribute__((ext_vector_type(4)));

static __device__ __forceinline__ unsigned short f2bf(float f) {
  __bf16 h = (__bf16)f;
  return __builtin_bit_cast(unsigned short, h);
}

static __device__ __forceinline__ ushort4 pk4(f32x4 v) {
  ushort4 o;
  o.x = f2bf(v.x); o.y = f2bf(v.y); o.z = f2bf(v.z); o.w = f2bf(v.w);
  return o;
}

static __device__ __forceinline__ void async16(const void* g, void* l) {
  __builtin_amdgcn_global_load_lds(
      (const __attribute__((address_space(1))) unsigned int*)g,
      (__attribute__((address_space(3))) unsigned int*)l, 16, 0, 0);
}

// ---------------- edge preprocessing (once per call) ----------------

__global__ __launch_bounds__(256) void k_hist(const int* __restrict__ ei,
                                              const int* __restrict__ et,
                                              int* __restrict__ cntNR) {
  int e = blockIdx.x * 256 + threadIdx.x;
  if (e >= NE) return;
  int dst = ei[NE + e];
  int r = et[e];
  atomicAdd(&cntNR[dst * 4 + r], 1);
}

__global__ __launch_bounds__(256) void k_scan1(const int* __restrict__ cntNR,
                                               int* __restrict__ offs,
                                               int* __restrict__ bsum) {
  __shared__ int sd[256];
  const int t = threadIdx.x;
  const int n = blockIdx.x * 256 + t;
  int deg = 0;
  if (n < NN) {
    const int* c = cntNR + n * 4;
    deg = c[0] + c[1] + c[2] + c[3];
  }
  sd[t] = deg;
  __syncthreads();
  int val = deg;
  for (int d = 1; d < 256; d <<= 1) {
    int other = (t >= d) ? sd[t - d] : 0;
    __syncthreads();
    val += other;
    sd[t] = val;
    __syncthreads();
  }
  if (n < NN) offs[n] = val - deg;  // exclusive
  if (t == 255) bsum[blockIdx.x] = val;
}

__global__ __launch_bounds__(256) void k_scan2(const int* __restrict__ bsum,
                                               int* __restrict__ boff, int nb) {
  __shared__ int sd[256];
  const int t = threadIdx.x;
  int v = (t < nb) ? bsum[t] : 0;
  sd[t] = v;
  __syncthreads();
  int val = v;
  for (int d = 1; d < 256; d <<= 1) {
    int other = (t >= d) ? sd[t - d] : 0;
    __syncthreads();
    val += other;
    sd[t] = val;
    __syncthreads();
  }
  boff[t] = val - v;  // exclusive
}

__global__ __launch_bounds__(256) void k_scan3(int* __restrict__ offs,
                                               const int* __restrict__ boff,
                                               int* __restrict__ cursor) {
  int n = blockIdx.x * 256 + threadIdx.x;
  if (n < NN) {
    int o = offs[n] + boff[blockIdx.x];
    offs[n] = o;
    cursor[n] = o;
  }
  if (n == 0) offs[NN] = NE;
}

__global__ __launch_bounds__(256) void k_scatter(const int* __restrict__ ei,
                                                 const int* __restrict__ et,
                                                 int* __restrict__ cursor,
                                                 uint32_t* __restrict__ packed) {
  int e = blockIdx.x * 256 + threadIdx.x;
  if (e >= NE) return;
  int src = ei[e];
  int dst = ei[NE + e];
  int r = et[e];
  int pos = atomicAdd(&cursor[dst], 1);
  packed[pos] = (uint32_t)src | ((uint32_t)r << 16);  // src < 65536 ok
}

// Build WbigT[l][o][k] bf16: k<1024 -> weights[l][k>>8][k&255][o], else roots[l][k-1024][o]
__global__ __launch_bounds__(256) void k_wconv(const float* __restrict__ weights,
                                               const float* __restrict__ roots,
                                               __hip_bfloat16* __restrict__ WbigT) {
  int idx = blockIdx.x * 256 + threadIdx.x;
  if (idx >= NL * DD * KT) return;
  int l = idx / (DD * KT);
  int rem = idx - l * (DD * KT);
  int o = rem / KT;
  int k = rem - o * KT;
  float v;
  if (k < NRL * DD) {
    int r = k >> 8, i = k & 255;
    v = weights[(((size_t)(l * NRL + r) * DD) + i) * DD + o];
  } else {
    int i = k - NRL * DD;
    v = roots[((size_t)l * DD + i) * DD + o];
  }
  WbigT[idx] = __float2bfloat16(v);
}

// one-time fp32 -> bf16 cast of the input embedding (4 elems/thread)
__global__ __launch_bounds__(256) void k_cast(const float* __restrict__ X,
                                              __hip_bfloat16* __restrict__ Xbf) {
  int i = blockIdx.x * 256 + threadIdx.x;
  if (i >= NN * 64) return;
  const f32x4* Xv = (const f32x4*)X;
  ((ushort4*)Xbf)[i] = pk4(Xv[i]);
}

// ---------------- per-layer aggregation: one wave per node, bf16 gather ----------------

__global__ __launch_bounds__(256) void k_agg(const __hip_bfloat16* __restrict__ Xbf,
                                             const uint32_t* __restrict__ packed,
                                             const int* __restrict__ offs,
                                             const int* __restrict__ cntNR,
                                             __hip_bfloat16* __restrict__ Abig) {
  const int wid = (blockIdx.x * 256 + threadIdx.x) >> 6;
  const int lane = threadIdx.x & 63;
  if (wid >= NN) return;
  const int beg = offs[wid];
  const int end = offs[wid + 1];
  const bf16x4* __restrict__ Xv = (const bf16x4*)Xbf;

  f32x4 a0 = {0.f, 0.f, 0.f, 0.f}, a1 = a0, a2 = a0, a3 = a0;

  uint32_t p = (beg < end) ? packed[beg] : 0u;
  for (int e = beg; e < end; ++e) {
    uint32_t pn = (e + 1 < end) ? packed[e + 1] : 0u;
    const int src = (int)(p & 0xFFFFu);
    const int r = (int)(p >> 16);  // wave-uniform -> cheap scalar branch
    bf16x4 bv = Xv[src * 64 + lane];
    f32x4 v = {(float)bv[0], (float)bv[1], (float)bv[2], (float)bv[3]};
    if (r == 0) a0 += v;
    else if (r == 1) a1 += v;
    else if (r == 2) a2 += v;
    else a3 += v;
    p = pn;
  }

  const int* c = cntNR + wid * 4;
  int c0 = c[0], c1 = c[1], c2 = c[2], c3 = c[3];
  float s0 = 1.0f / (float)(c0 > 1 ? c0 : 1);
  float s1 = 1.0f / (float)(c1 > 1 ? c1 : 1);
  float s2 = 1.0f / (float)(c2 > 1 ? c2 : 1);
  float s3 = 1.0f / (float)(c3 > 1 ? c3 : 1);

  ushort4* Arow = (ushort4*)(Abig + (size_t)wid * KA);
  Arow[0 * 64 + lane] = pk4(a0 * s0);
  Arow[1 * 64 + lane] = pk4(a1 * s1);
  Arow[2 * 64 + lane] = pk4(a2 * s2);
  Arow[3 * 64 + lane] = pk4(a3 * s3);
}

// ---------------- GEMM + bias + LayerNorm + ELU + residual (+ bf16 X for next layer) ----
// C[m, n] = [Abig | Xbf][m, 0:1280] @ WbigT[n, 0:1280]^T ; BM=64, BN=256, BK=32

__global__ __launch_bounds__(256) void k_gemm(const __hip_bfloat16* __restrict__ A,
                                              const __hip_bfloat16* __restrict__ Xbf_in,
                                              const __hip_bfloat16* __restrict__ Bt,
                                              const float* __restrict__ bias,
                                              const float* __restrict__ gamma,
                                              const float* __restrict__ beta,
                                              const float* __restrict__ Xin,
                                              float* __restrict__ Xout,
                                              __hip_bfloat16* __restrict__ Xbf_out) {
  __shared__ __align__(16) char sA[64 * 64];    // 64 rows x 32 bf16 (64B), chunk-swizzled
  __shared__ __align__(16) char sB[256 * 64];   // 256 rows x 32 bf16
  __shared__ float sRed[64][4];

  const int tid = threadIdx.x;
  const int w = tid >> 6;
  const int lane = tid & 63;
  const int wm = w >> 1, wn = w & 1;
  const int quad = lane >> 4, l15 = lane & 15;
  const int mBase = blockIdx.x * 64;

  // staging lane map: lane i -> row i/4, LDS slot i%4; global chunk = slot ^ ((row>>1)&3)
  const int srow = lane >> 2;
  const int kc = (lane & 3) ^ ((lane >> 3) & 3);

  int am = mBase + w * 16 + srow;
  if (am >= NN) am = NN - 1;  // clamp (stores are guarded)
  const char* agp = (const char*)A + (size_t)am * (KA * 2) + kc * 16;
  const char* agx = (const char*)Xbf_in + (size_t)am * (DD * 2) + kc * 16;
  const char* bgp0 = (const char*)Bt + (size_t)(w * 64 + 0 + srow) * (KT * 2) + kc * 16;
  const char* bgp1 = (const char*)Bt + (size_t)(w * 64 + 16 + srow) * (KT * 2) + kc * 16;
  const char* bgp2 = (const char*)Bt + (size_t)(w * 64 + 32 + srow) * (KT * 2) + kc * 16;
  const char* bgp3 = (const char*)Bt + (size_t)(w * 64 + 48 + srow) * (KT * 2) + kc * 16;
  char* alp = sA + w * 1024;
  char* blp0 = sB + w * 4096 + 0;
  char* blp1 = sB + w * 4096 + 1024;
  char* blp2 = sB + w * 4096 + 2048;
  char* blp3 = sB + w * 4096 + 3072;

  f32x4 acc[2][8];
#pragma unroll
  for (int i = 0; i < 2; ++i)
#pragma unroll
    for (int j = 0; j < 8; ++j) acc[i][j] = (f32x4){0.f, 0.f, 0.f, 0.f};

  const int aslot = (quad ^ ((l15 >> 1) & 3)) * 16;
  const char* aAddr0 = sA + (wm * 32 + 0 + l15) * 64 + aslot;
  const char* aAddr1 = sA + (wm * 32 + 16 + l15) * 64 + aslot;
  const char* bAddr = sB + (wn * 128 + l15) * 64 + aslot;

  for (int k0 = 0; k0 < KT * 2; k0 += 64) {  // byte offset within the logical K row
    // A source: cols 0..1023 live in Abig (row stride 2048B), 1024..1279 in Xbf (stride 512B)
    const char* ap = (k0 < KA * 2) ? (agp + k0) : (agx + (k0 - KA * 2));
    __syncthreads();
    async16(ap, alp);
    async16(bgp0 + k0, blp0);
    async16(bgp1 + k0, blp1);
    async16(bgp2 + k0, blp2);
    async16(bgp3 + k0, blp3);
    __syncthreads();
    bf16x8 a0 = *(const bf16x8*)aAddr0;
    bf16x8 a1 = *(const bf16x8*)aAddr1;
#pragma unroll
    for (int nt = 0; nt < 8; ++nt) {
      bf16x8 b = *(const bf16x8*)(bAddr + nt * 1024);
      acc[0][nt] = __builtin_amdgcn_mfma_f32_16x16x32_bf16(a0, b, acc[0][nt], 0, 0, 0);
      acc[1][nt] = __builtin_amdgcn_mfma_f32_16x16x32_bf16(a1, b, acc[1][nt], 0, 0, 0);
    }
  }

  // ---- epilogue: bias, LN (full 256-wide rows in-block), ELU, residual ----
  float bv[8], gv[8], bev[8];
#pragma unroll
  for (int nt = 0; nt < 8; ++nt) {
    int n = wn * 128 + nt * 16 + l15;
    bv[nt] = bias[n];
    gv[nt] = gamma[n];
    bev[nt] = beta[n];
  }

#pragma unroll
  for (int mt = 0; mt < 2; ++mt) {
#pragma unroll
    for (int reg = 0; reg < 4; ++reg) {
      float s = 0.f, q = 0.f;
#pragma unroll
      for (int nt = 0; nt < 8; ++nt) {
        float v = acc[mt][nt][reg] + bv[nt];
        acc[mt][nt][reg] = v;
        s += v;
        q += v * v;
      }
#pragma unroll
      for (int d = 1; d < 16; d <<= 1) {
        s += __shfl_xor(s, d, 64);
        q += __shfl_xor(q, d, 64);
      }
      if (l15 == 0) {
        int row = wm * 32 + mt * 16 + quad * 4 + reg;
        sRed[row][wn * 2] = s;
        sRed[row][wn * 2 + 1] = q;
      }
    }
  }
  __syncthreads();

#pragma unroll
  for (int mt = 0; mt < 2; ++mt) {
#pragma unroll
    for (int reg = 0; reg < 4; ++reg) {
      int row = wm * 32 + mt * 16 + quad * 4 + reg;
      float ts = sRed[row][0] + sRed[row][2];
      float tq = sRed[row][1] + sRed[row][3];
      float mean = ts * (1.0f / 256.0f);
      float var = tq * (1.0f / 256.0f) - mean * mean;
      float rstd = rsqrtf(var + 1e-5f);
      int m = mBase + row;
      if (m < NN) {
#pragma unroll
        for (int nt = 0; nt < 8; ++nt) {
          int n = wn * 128 + nt * 16 + l15;
          float v = (acc[mt][nt][reg] - mean) * rstd * gv[nt] + bev[nt];
          v = v > 0.0f ? v : (__expf(v) - 1.0f);
          float res = v + Xin[(size_t)m * 256 + n];
          Xout[(size_t)m * 256 + n] = res;
          Xbf_out[(size_t)m * 256 + n] = __float2bfloat16(res);
        }
      }
    }
  }
}

// ---------------- host side ----------------

extern "C" void kernel_launch(void* const* d_in, const int* in_sizes, int n_in,
                              void* d_out, int out_size, void* d_ws, size_t ws_size,
                              hipStream_t stream) {
  const float* X0 = (const float*)d_in[0];
  const float* weights = (const float*)d_in[1];
  const float* roots = (const float*)d_in[2];
  const float* biases = (const float*)d_in[3];
  const float* ln_g = (const float*)d_in[4];
  const float* ln_b = (const float*)d_in[5];
  const int* eidx = (const int*)d_in[6];
  const int* etyp = (const int*)d_in[7];
  float* out = (float*)d_out;

  char* ws = (char*)d_ws;
  size_t off = 0;
  auto alloc = [&](size_t bytes) -> char* {
    char* p = ws + off;
    off = (off + bytes + 255) & ~(size_t)255;
    return p;
  };
  __hip_bfloat16* Abig = (__hip_bfloat16*)alloc((size_t)NN * KA * 2);          // 102.4 MB
  __hip_bfloat16* WbigT = (__hip_bfloat16*)alloc((size_t)NL * DD * KT * 2);    // 2.6 MB
  float* Xb0 = (float*)alloc((size_t)NN * DD * 4);                              // 51.2 MB
  float* Xb1 = (float*)alloc((size_t)NN * DD * 4);                              // 51.2 MB
  __hip_bfloat16* Xbf0 = (__hip_bfloat16*)alloc((size_t)NN * DD * 2);           // 25.6 MB
  __hip_bfloat16* Xbf1 = (__hip_bfloat16*)alloc((size_t)NN * DD * 2);           // 25.6 MB
  int* cntNR = (int*)alloc((size_t)NN * 4 * 4);
  int* offs = (int*)alloc((size_t)(NN + 1) * 4);
  int* cursor = (int*)alloc((size_t)NN * 4);
  uint32_t* packed = (uint32_t*)alloc((size_t)NE * 4);
  int* bsum = (int*)alloc(256 * 4);
  int* boff = (int*)alloc(256 * 4);
  (void)ws_size; (void)in_sizes; (void)n_in; (void)out_size;

  hipMemsetAsync(cntNR, 0, (size_t)NN * 16, stream);
  k_hist<<<(NE + 255) / 256, 256, 0, stream>>>(eidx, etyp, cntNR);
  const int NB = (NN + 255) / 256;  // 196
  k_scan1<<<NB, 256, 0, stream>>>(cntNR, offs, bsum);
  k_scan2<<<1, 256, 0, stream>>>(bsum, boff, NB);
  k_scan3<<<NB, 256, 0, stream>>>(offs, boff, cursor);
  k_scatter<<<(NE + 255) / 256, 256, 0, stream>>>(eidx, etyp, cursor, packed);
  k_wconv<<<(NL * DD * KT + 255) / 256, 256, 0, stream>>>(weights, roots, WbigT);
  k_cast<<<(NN * 64 + 255) / 256, 256, 0, stream>>>(X0, Xbf0);

  const float* Xin = X0;
  for (int l = 0; l < NL; ++l) {
    float* Xout = (l == NL - 1) ? out : ((l & 1) ? Xb1 : Xb0);
    const __hip_bfloat16* Xbin = (l & 1) ? Xbf1 : Xbf0;
    __hip_bfloat16* Xbout = (l & 1) ? Xbf0 : Xbf1;
    k_agg<<<(NN * 64 + 255) / 256, 256, 0, stream>>>(Xbin, packed, offs, cntNR, Abig);
    k_gemm<<<(NN + 63) / 64, 256, 0, stream>>>(Abig, Xbin,
                                               WbigT + (size_t)l * DD * KT,
                                               biases + (size_t)l * DD,
                                               ln_g + (size_t)l * DD,
                                               ln_b + (size_t)l * DD, Xin, Xout, Xbout);
    Xin = Xout;
  }
}

// Round 4
// 970.476 us; speedup vs baseline: 1.0949x; 1.0432x over previous
//
#include <hip/hip_runtime.h>
#include <hip/hip_bf16.h>
#include <stdint.h>

#define NN 50000
#define NE 800000
#define DD 256
#define NL 4
#define NRL 4
#define KT 1280  // NRL*DD + DD (logical K of the fused GEMM)
#define KA 1024  // NRL*DD (columns stored in Abig; root block comes from Xbf)

typedef float f32x4 __attribute__((ext_vector_type(4)));
typedef __bf16 bf16x8 __attribute__((ext_vector_type(8)));
typedef __bf16 bf16x4 __attribute__((ext_vector_type(4)));
typedef unsigned short u16x4 __attribute__((ext_vector_type(4)));

static __device__ __forceinline__ unsigned short f2bf(float f) {
  __bf16 h = (__bf16)f;
  return __builtin_bit_cast(unsigned short, h);
}

static __device__ __forceinline__ u16x4 pk4(f32x4 v) {
  u16x4 o;
  o.x = f2bf(v.x); o.y = f2bf(v.y); o.z = f2bf(v.z); o.w = f2bf(v.w);
  return o;
}

static __device__ __forceinline__ void async16(const void* g, void* l) {
  __builtin_amdgcn_global_load_lds(
      (const __attribute__((address_space(1))) unsigned int*)g,
      (__attribute__((address_space(3))) unsigned int*)l, 16, 0, 0);
}

// nt-hint variant (aux bit1 = NT on gfx94x/gfx950): stream, don't allocate in cache
static __device__ __forceinline__ void async16nt(const void* g, void* l) {
  __builtin_amdgcn_global_load_lds(
      (const __attribute__((address_space(1))) unsigned int*)g,
      (__attribute__((address_space(3))) unsigned int*)l, 16, 0, 2);
}

// ---------------- edge preprocessing (once per call) ----------------

__global__ __launch_bounds__(256) void k_hist(const int* __restrict__ ei,
                                              const int* __restrict__ et,
                                              int* __restrict__ cntNR) {
  int e = blockIdx.x * 256 + threadIdx.x;
  if (e >= NE) return;
  int dst = ei[NE + e];
  int r = et[e];
  atomicAdd(&cntNR[dst * 4 + r], 1);
}

__global__ __launch_bounds__(256) void k_scan1(const int* __restrict__ cntNR,
                                               int* __restrict__ offs,
                                               int* __restrict__ bsum) {
  __shared__ int sd[256];
  const int t = threadIdx.x;
  const int n = blockIdx.x * 256 + t;
  int deg = 0;
  if (n < NN) {
    const int* c = cntNR + n * 4;
    deg = c[0] + c[1] + c[2] + c[3];
  }
  sd[t] = deg;
  __syncthreads();
  int val = deg;
  for (int d = 1; d < 256; d <<= 1) {
    int other = (t >= d) ? sd[t - d] : 0;
    __syncthreads();
    val += other;
    sd[t] = val;
    __syncthreads();
  }
  if (n < NN) offs[n] = val - deg;  // exclusive
  if (t == 255) bsum[blockIdx.x] = val;
}

__global__ __launch_bounds__(256) void k_scan2(const int* __restrict__ bsum,
                                               int* __restrict__ boff, int nb) {
  __shared__ int sd[256];
  const int t = threadIdx.x;
  int v = (t < nb) ? bsum[t] : 0;
  sd[t] = v;
  __syncthreads();
  int val = v;
  for (int d = 1; d < 256; d <<= 1) {
    int other = (t >= d) ? sd[t - d] : 0;
    __syncthreads();
    val += other;
    sd[t] = val;
    __syncthreads();
  }
  boff[t] = val - v;  // exclusive
}

__global__ __launch_bounds__(256) void k_scan3(int* __restrict__ offs,
                                               const int* __restrict__ boff,
                                               int* __restrict__ cursor) {
  int n = blockIdx.x * 256 + threadIdx.x;
  if (n < NN) {
    int o = offs[n] + boff[blockIdx.x];
    offs[n] = o;
    cursor[n] = o;
  }
  if (n == 0) offs[NN] = NE;
}

__global__ __launch_bounds__(256) void k_scatter(const int* __restrict__ ei,
                                                 const int* __restrict__ et,
                                                 int* __restrict__ cursor,
                                                 uint32_t* __restrict__ packed) {
  int e = blockIdx.x * 256 + threadIdx.x;
  if (e >= NE) return;
  int src = ei[e];
  int dst = ei[NE + e];
  int r = et[e];
  int pos = atomicAdd(&cursor[dst], 1);
  packed[pos] = (uint32_t)src | ((uint32_t)r << 16);  // src < 65536 ok
}

// Build WbigT[l][o][k] bf16: k<1024 -> weights[l][k>>8][k&255][o], else roots[l][k-1024][o]
__global__ __launch_bounds__(256) void k_wconv(const float* __restrict__ weights,
                                               const float* __restrict__ roots,
                                               __hip_bfloat16* __restrict__ WbigT) {
  int idx = blockIdx.x * 256 + threadIdx.x;
  if (idx >= NL * DD * KT) return;
  int l = idx / (DD * KT);
  int rem = idx - l * (DD * KT);
  int o = rem / KT;
  int k = rem - o * KT;
  float v;
  if (k < NRL * DD) {
    int r = k >> 8, i = k & 255;
    v = weights[(((size_t)(l * NRL + r) * DD) + i) * DD + o];
  } else {
    int i = k - NRL * DD;
    v = roots[((size_t)l * DD + i) * DD + o];
  }
  WbigT[idx] = __float2bfloat16(v);
}

// one-time fp32 -> bf16 cast of the input embedding (4 elems/thread)
__global__ __launch_bounds__(256) void k_cast(const float* __restrict__ X,
                                              __hip_bfloat16* __restrict__ Xbf) {
  int i = blockIdx.x * 256 + threadIdx.x;
  if (i >= NN * 64) return;
  const f32x4* Xv = (const f32x4*)X;
  ((u16x4*)Xbf)[i] = pk4(Xv[i]);
}

// ---------------- per-layer aggregation: one wave per node, pipelined bf16 gather ------

__global__ __launch_bounds__(256) void k_agg(const __hip_bfloat16* __restrict__ Xbf,
                                             const uint32_t* __restrict__ packed,
                                             const int* __restrict__ offs,
                                             const int* __restrict__ cntNR,
                                             __hip_bfloat16* __restrict__ Abig) {
  const int wid = (blockIdx.x * 256 + threadIdx.x) >> 6;
  const int lane = threadIdx.x & 63;
  if (wid >= NN) return;
  const int beg = offs[wid];
  const int end = offs[wid + 1];
  const bf16x4* __restrict__ Xv = (const bf16x4*)Xbf;

  f32x4 a0 = {0.f, 0.f, 0.f, 0.f}, a1 = a0, a2 = a0, a3 = a0;

  // depth-8 software pipeline: 8 packed loads, then 8 row-gathers in flight,
  // then accumulate (r is wave-uniform -> scalar branch)
  for (int e = beg; e < end; e += 8) {
    uint32_t pv[8];
    bf16x4 vv[8];
#pragma unroll
    for (int i = 0; i < 8; ++i) {
      int ee = e + i;
      ee = (ee < end) ? ee : (end - 1);
      pv[i] = packed[ee];
    }
#pragma unroll
    for (int i = 0; i < 8; ++i) {
      vv[i] = Xv[(int)(pv[i] & 0xFFFFu) * 64 + lane];
    }
    const int nv = end - e;
#pragma unroll
    for (int i = 0; i < 8; ++i) {
      if (i < nv) {
        int r = (int)(pv[i] >> 16);
        f32x4 v = {(float)vv[i][0], (float)vv[i][1], (float)vv[i][2], (float)vv[i][3]};
        if (r == 0) a0 += v;
        else if (r == 1) a1 += v;
        else if (r == 2) a2 += v;
        else a3 += v;
      }
    }
  }

  const int* c = cntNR + wid * 4;
  int c0 = c[0], c1 = c[1], c2 = c[2], c3 = c[3];
  float s0 = 1.0f / (float)(c0 > 1 ? c0 : 1);
  float s1 = 1.0f / (float)(c1 > 1 ? c1 : 1);
  float s2 = 1.0f / (float)(c2 > 1 ? c2 : 1);
  float s3 = 1.0f / (float)(c3 > 1 ? c3 : 1);

  // nt stores: don't let the 100MB Abig stream evict Xbf from L3
  u16x4* Arow = (u16x4*)(Abig + (size_t)wid * KA);
  __builtin_nontemporal_store(pk4(a0 * s0), Arow + 0 * 64 + lane);
  __builtin_nontemporal_store(pk4(a1 * s1), Arow + 1 * 64 + lane);
  __builtin_nontemporal_store(pk4(a2 * s2), Arow + 2 * 64 + lane);
  __builtin_nontemporal_store(pk4(a3 * s3), Arow + 3 * 64 + lane);
}

// ---------------- GEMM + bias + LayerNorm + ELU + residual (+ bf16 X for next layer) ----
// C[m, n] = [Abig | Xbf][m, 0:1280] @ WbigT[n, 0:1280]^T ; BM=128, BN=256, BK=32
// 4 waves in 2x2: each wave 64 rows x 128 cols = 4x8 MFMA tiles

__global__ __launch_bounds__(256) void k_gemm(const __hip_bfloat16* __restrict__ A,
                                              const __hip_bfloat16* __restrict__ Xbf_in,
                                              const __hip_bfloat16* __restrict__ Bt,
                                              const float* __restrict__ bias,
                                              const float* __restrict__ gamma,
                                              const float* __restrict__ beta,
                                              const float* __restrict__ Xin,
                                              float* __restrict__ Xout,
                                              __hip_bfloat16* __restrict__ Xbf_out) {
  __shared__ __align__(16) char sA[128 * 64];   // 128 rows x 32 bf16 (64B), chunk-swizzled
  __shared__ __align__(16) char sB[256 * 64];   // 256 rows x 32 bf16
  __shared__ float sRed[128][4];

  const int tid = threadIdx.x;
  const int w = tid >> 6;
  const int lane = tid & 63;
  const int wm = w >> 1, wn = w & 1;
  const int quad = lane >> 4, l15 = lane & 15;
  const int mBase = blockIdx.x * 128;

  // staging lane map: lane i -> row i/4, LDS slot i%4; global chunk = slot ^ ((row>>1)&3)
  const int srow = lane >> 2;
  const int kc = (lane & 3) ^ ((lane >> 3) & 3);

  int am0 = mBase + w * 32 + srow;
  int am1 = am0 + 16;
  if (am0 >= NN) am0 = NN - 1;  // clamp (stores are guarded)
  if (am1 >= NN) am1 = NN - 1;
  const char* agp0 = (const char*)A + (size_t)am0 * (KA * 2) + kc * 16;
  const char* agp1 = (const char*)A + (size_t)am1 * (KA * 2) + kc * 16;
  const char* agx0 = (const char*)Xbf_in + (size_t)am0 * (DD * 2) + kc * 16;
  const char* agx1 = (const char*)Xbf_in + (size_t)am1 * (DD * 2) + kc * 16;
  const char* bgp0 = (const char*)Bt + (size_t)(w * 64 + 0 + srow) * (KT * 2) + kc * 16;
  const char* bgp1 = (const char*)Bt + (size_t)(w * 64 + 16 + srow) * (KT * 2) + kc * 16;
  const char* bgp2 = (const char*)Bt + (size_t)(w * 64 + 32 + srow) * (KT * 2) + kc * 16;
  const char* bgp3 = (const char*)Bt + (size_t)(w * 64 + 48 + srow) * (KT * 2) + kc * 16;
  char* alp0 = sA + w * 2048;
  char* alp1 = sA + w * 2048 + 1024;
  char* blp0 = sB + w * 4096 + 0;
  char* blp1 = sB + w * 4096 + 1024;
  char* blp2 = sB + w * 4096 + 2048;
  char* blp3 = sB + w * 4096 + 3072;

  f32x4 acc[4][8];
#pragma unroll
  for (int i = 0; i < 4; ++i)
#pragma unroll
    for (int j = 0; j < 8; ++j) acc[i][j] = (f32x4){0.f, 0.f, 0.f, 0.f};

  const int aslot = (quad ^ ((l15 >> 1) & 3)) * 16;
  const char* aAddr = sA + (wm * 64 + l15) * 64 + aslot;   // + mt*1024
  const char* bAddr = sB + (wn * 128 + l15) * 64 + aslot;  // + nt*1024

  for (int k0 = 0; k0 < KT * 2; k0 += 64) {  // byte offset within the logical K row
    __syncthreads();
    if (k0 < KA * 2) {  // cols 0..1023 from Abig (nt: read once, don't pollute L3)
      async16nt(agp0 + k0, alp0);
      async16nt(agp1 + k0, alp1);
    } else {            // cols 1024..1279 from Xbf (keep cached)
      const int kx = k0 - KA * 2;
      async16(agx0 + kx, alp0);
      async16(agx1 + kx, alp1);
    }
    async16(bgp0 + k0, blp0);
    async16(bgp1 + k0, blp1);
    async16(bgp2 + k0, blp2);
    async16(bgp3 + k0, blp3);
    __syncthreads();
    bf16x8 a0 = *(const bf16x8*)(aAddr + 0 * 1024);
    bf16x8 a1 = *(const bf16x8*)(aAddr + 1 * 1024);
    bf16x8 a2 = *(const bf16x8*)(aAddr + 2 * 1024);
    bf16x8 a3 = *(const bf16x8*)(aAddr + 3 * 1024);
#pragma unroll
    for (int nt = 0; nt < 8; ++nt) {
      bf16x8 b = *(const bf16x8*)(bAddr + nt * 1024);
      acc[0][nt] = __builtin_amdgcn_mfma_f32_16x16x32_bf16(a0, b, acc[0][nt], 0, 0, 0);
      acc[1][nt] = __builtin_amdgcn_mfma_f32_16x16x32_bf16(a1, b, acc[1][nt], 0, 0, 0);
      acc[2][nt] = __builtin_amdgcn_mfma_f32_16x16x32_bf16(a2, b, acc[2][nt], 0, 0, 0);
      acc[3][nt] = __builtin_amdgcn_mfma_f32_16x16x32_bf16(a3, b, acc[3][nt], 0, 0, 0);
    }
  }

  // ---- epilogue: bias, LN (full 256-wide rows in-block), ELU, residual ----
  float bv[8], gv[8], bev[8];
#pragma unroll
  for (int nt = 0; nt < 8; ++nt) {
    int n = wn * 128 + nt * 16 + l15;
    bv[nt] = bias[n];
    gv[nt] = gamma[n];
    bev[nt] = beta[n];
  }

#pragma unroll
  for (int mt = 0; mt < 4; ++mt) {
#pragma unroll
    for (int reg = 0; reg < 4; ++reg) {
      float s = 0.f, q = 0.f;
#pragma unroll
      for (int nt = 0; nt < 8; ++nt) {
        float v = acc[mt][nt][reg] + bv[nt];
        acc[mt][nt][reg] = v;
        s += v;
        q += v * v;
      }
#pragma unroll
      for (int d = 1; d < 16; d <<= 1) {
        s += __shfl_xor(s, d, 64);
        q += __shfl_xor(q, d, 64);
      }
      if (l15 == 0) {
        int row = wm * 64 + mt * 16 + quad * 4 + reg;
        sRed[row][wn * 2] = s;
        sRed[row][wn * 2 + 1] = q;
      }
    }
  }
  __syncthreads();

#pragma unroll
  for (int mt = 0; mt < 4; ++mt) {
#pragma unroll
    for (int reg = 0; reg < 4; ++reg) {
      int row = wm * 64 + mt * 16 + quad * 4 + reg;
      float ts = sRed[row][0] + sRed[row][2];
      float tq = sRed[row][1] + sRed[row][3];
      float mean = ts * (1.0f / 256.0f);
      float var = tq * (1.0f / 256.0f) - mean * mean;
      float rstd = rsqrtf(var + 1e-5f);
      int m = mBase + row;
      if (m < NN) {
#pragma unroll
        for (int nt = 0; nt < 8; ++nt) {
          int n = wn * 128 + nt * 16 + l15;
          float v = (acc[mt][nt][reg] - mean) * rstd * gv[nt] + bev[nt];
          v = v > 0.0f ? v : (__expf(v) - 1.0f);
          float res = v + Xin[(size_t)m * 256 + n];
          Xout[(size_t)m * 256 + n] = res;
          Xbf_out[(size_t)m * 256 + n] = __float2bfloat16(res);
        }
      }
    }
  }
}

// ---------------- host side ----------------

extern "C" void kernel_launch(void* const* d_in, const int* in_sizes, int n_in,
                              void* d_out, int out_size, void* d_ws, size_t ws_size,
                              hipStream_t stream) {
  const float* X0 = (const float*)d_in[0];
  const float* weights = (const float*)d_in[1];
  const float* roots = (const float*)d_in[2];
  const float* biases = (const float*)d_in[3];
  const float* ln_g = (const float*)d_in[4];
  const float* ln_b = (const float*)d_in[5];
  const int* eidx = (const int*)d_in[6];
  const int* etyp = (const int*)d_in[7];
  float* out = (float*)d_out;

  char* ws = (char*)d_ws;
  size_t off = 0;
  auto alloc = [&](size_t bytes) -> char* {
    char* p = ws + off;
    off = (off + bytes + 255) & ~(size_t)255;
    return p;
  };
  __hip_bfloat16* Abig = (__hip_bfloat16*)alloc((size_t)NN * KA * 2);          // 102.4 MB
  __hip_bfloat16* WbigT = (__hip_bfloat16*)alloc((size_t)NL * DD * KT * 2);    // 2.6 MB
  float* Xb0 = (float*)alloc((size_t)NN * DD * 4);                              // 51.2 MB
  float* Xb1 = (float*)alloc((size_t)NN * DD * 4);                              // 51.2 MB
  __hip_bfloat16* Xbf0 = (__hip_bfloat16*)alloc((size_t)NN * DD * 2);           // 25.6 MB
  __hip_bfloat16* Xbf1 = (__hip_bfloat16*)alloc((size_t)NN * DD * 2);           // 25.6 MB
  int* cntNR = (int*)alloc((size_t)NN * 4 * 4);
  int* offs = (int*)alloc((size_t)(NN + 1) * 4);
  int* cursor = (int*)alloc((size_t)NN * 4);
  uint32_t* packed = (uint32_t*)alloc((size_t)NE * 4);
  int* bsum = (int*)alloc(256 * 4);
  int* boff = (int*)alloc(256 * 4);
  (void)ws_size; (void)in_sizes; (void)n_in; (void)out_size;

  (void)hipMemsetAsync(cntNR, 0, (size_t)NN * 16, stream);
  k_hist<<<(NE + 255) / 256, 256, 0, stream>>>(eidx, etyp, cntNR);
  const int NB = (NN + 255) / 256;  // 196
  k_scan1<<<NB, 256, 0, stream>>>(cntNR, offs, bsum);
  k_scan2<<<1, 256, 0, stream>>>(bsum, boff, NB);
  k_scan3<<<NB, 256, 0, stream>>>(offs, boff, cursor);
  k_scatter<<<(NE + 255) / 256, 256, 0, stream>>>(eidx, etyp, cursor, packed);
  k_wconv<<<(NL * DD * KT + 255) / 256, 256, 0, stream>>>(weights, roots, WbigT);
  k_cast<<<(NN * 64 + 255) / 256, 256, 0, stream>>>(X0, Xbf0);

  const float* Xin = X0;
  for (int l = 0; l < NL; ++l) {
    float* Xout = (l == NL - 1) ? out : ((l & 1) ? Xb1 : Xb0);
    const __hip_bfloat16* Xbin = (l & 1) ? Xbf1 : Xbf0;
    __hip_bfloat16* Xbout = (l & 1) ? Xbf0 : Xbf1;
    k_agg<<<(NN * 64 + 255) / 256, 256, 0, stream>>>(Xbin, packed, offs, cntNR, Abig);
    k_gemm<<<(NN + 127) / 128, 256, 0, stream>>>(Abig, Xbin,
                                                 WbigT + (size_t)l * DD * KT,
                                                 biases + (size_t)l * DD,
                                                 ln_g + (size_t)l * DD,
                                                 ln_b + (size_t)l * DD, Xin, Xout, Xbout);
    Xin = Xout;
  }
}